// Round 12
// baseline (454.453 us; speedup 1.0000x reference)
//
#include <hip/hip_runtime.h>

// LSTM B=2048, T=1024, H=50. Round 12: 4 uniform waves, halved LDS burst.
//
// grid=256 (1 block/CU), block=256 = 4 waves, BW=8 batches.
// 16 permuted gate-row tiles (rows n'=4j+g; tiles 13-15 = zero-pad, units
// j=52..63). Wave w owns tiles T = w, w+4, w+8, w+12 — all waves IDENTICAL
// (no skew). Lane (kq, L15): cp=(L15>>3)&1 selects acc pair statically:
//   pair0 = cp?acc1:acc0 -> unit j0 = 4w + 16cp + kq  (always < 32)
//   pair1 = cp?acc3:acc2 -> unit j1 = j0 + 32         (< 50 guarded for head)
// 2 independent 7-trans epilogue chains per lane (ILP). h written unguarded:
// pad units land in k=50..63 slots whose A-columns are zero.
// A = scaled W' single f16 in VGPRs (i,f,o rows x -log2e; g rows x +2log2e).
// x/bias: exact fp32 epilogue FMAs (gate = acc + fma(s*wih, x, s*bias));
// every lane register-prefetches its own batch's x row — NO x LDS machinery.
// hb stride KP=80 f16 (40 words, R10/R11-measured conflict-free).
// Per step: 2 ds_read_b128 + 8 MFMA (4 indep 2-deep chains) + 8 cndmask +
// 16 gate-FMA/add + 14 trans + ~20 VALU + 2 ds_write_b16 + 1 barrier.

#define H     50
#define TT    1024
#define BATCH 2048
#define BW    8
#define NTHR  256     // 4 waves
#define KP    80      // f16 per hb row (40-word stride, measured free)

typedef float    f32x4 __attribute__((ext_vector_type(4)));
typedef _Float16 f16x8 __attribute__((ext_vector_type(8)));

__global__ __launch_bounds__(NTHR, 1) void lstm_kernel(
    const float* __restrict__ x,      // [B, T]
    const float* __restrict__ W_ih,   // [200]
    const float* __restrict__ W_hh,   // [200, 50]
    const float* __restrict__ b_ih,   // [200]
    const float* __restrict__ b_hh,   // [200]
    const float* __restrict__ W_lin,  // [50]
    const float* __restrict__ b_lin,  // [1]
    float* __restrict__ out)          // [B]
{
    __shared__ _Float16 hb[2][BW][KP];   // h^T, double-buffered
    __shared__ float    redH[H][BW];     // head reduction

    const int tid  = threadIdx.x;
    const int wave = tid >> 6;
    const int lane = tid & 63;
    const int L15  = lane & 15;
    const int kq   = lane >> 4;
    const int bl   = L15 & 7;            // this lane's batch
    const int cp   = (L15 >> 3) & 1;     // copy bit -> tile select
    const int b0   = blockIdx.x * BW;

    const float LOG2E  = 1.4426950408889634f;
    const float LOG2E2 = 2.8853900817779268f;

    // ---- A fragments: scaled permuted W' rows, single f16, in VGPRs ----
    // tile i: T = wave + 4i; A[m=L15][k=kf*32+kq*8+e], row m=16T+L15 = 4j+g.
    // Only k<50 nonzero (x/bias NOT in the MFMA this round).
    f16x8 A[4][2];
    #pragma unroll
    for (int i = 0; i < 4; ++i) {
        const int T  = wave + 4 * i;
        const int m  = T * 16 + L15;
        const int jm = m >> 2, gm = m & 3;
        const bool v = (jm < H);
        const float s = (gm == 2) ? LOG2E2 : -LOG2E;
        #pragma unroll
        for (int kf = 0; kf < 2; ++kf) {
            f16x8 vv;
            #pragma unroll
            for (int e = 0; e < 8; ++e) {
                const int k = kf * 32 + kq * 8 + e;
                vv[e] = (v && k < H)
                    ? (_Float16)(s * W_hh[(gm * H + jm) * H + k])
                    : (_Float16)0.f;
            }
            A[i][kf] = vv;
        }
    }

    // ---- this lane's two pairs ----
    const int  j0  = 4 * wave + 16 * cp + kq;   // 0..31, always valid
    const int  j1  = j0 + 32;                   // 32..63, valid if < 50
    const bool jv1 = (j1 < H);

    // per-gate scaled consts: gate g of unit j uses s_g = (g==2?+:-)log2e(*2)
    float swA[4], sbA[4], swB[4], sbB[4];
    #pragma unroll
    for (int g = 0; g < 4; ++g) {
        const float sg = (g == 2) ? LOG2E2 : -LOG2E;
        swA[g] = sg * W_ih[g * H + j0];
        sbA[g] = sg * (b_ih[g * H + j0] + b_hh[g * H + j0]);
        swB[g] = jv1 ? sg * W_ih[g * H + j1] : 0.f;
        sbB[g] = jv1 ? sg * (b_ih[g * H + j1] + b_hh[g * H + j1]) : 0.f;
    }
    const float wlinA = W_lin[j0];
    const float wlinB = jv1 ? W_lin[j1] : 0.f;

    // ---- init: zero both h buffers (h0 = 0; pad slots stay vs zero-A) ----
    for (int i = tid; i < 2 * BW * KP; i += NTHR)
        ((_Float16*)hb)[i] = (_Float16)0.f;

    // ---- x prefetch: every lane holds its own batch row, 4 steps ahead ----
    const float* xrow = x + (size_t)(b0 + bl) * TT;
    float4 xq  = *(const float4*)(xrow);       // x[0..3]
    float4 xq2 = *(const float4*)(xrow + 4);   // x[4..7]

    float c0 = 0.f, c1 = 0.f, hA = 0.f, hBv = 0.f;
    __syncthreads();

    for (int t = 0; t < TT; ++t) {
        // ---- B fragments (broadcast pairs L15 / L15+8 -> same row) ----
        const _Float16* hp = &hb[t & 1][bl][0];
        f16x8 B0 = *(const f16x8*)(hp + kq * 8);        // k 0..31
        f16x8 B1 = *(const f16x8*)(hp + 32 + kq * 8);   // k 32..63

        // ---- 8 MFMAs: four independent 2-deep chains ----
        const f32x4 z = {0.f, 0.f, 0.f, 0.f};
        f32x4 a0 = __builtin_amdgcn_mfma_f32_16x16x32_f16(A[0][0], B0, z, 0, 0, 0);
        f32x4 a1 = __builtin_amdgcn_mfma_f32_16x16x32_f16(A[1][0], B0, z, 0, 0, 0);
        f32x4 a2 = __builtin_amdgcn_mfma_f32_16x16x32_f16(A[2][0], B0, z, 0, 0, 0);
        f32x4 a3 = __builtin_amdgcn_mfma_f32_16x16x32_f16(A[3][0], B0, z, 0, 0, 0);
        a0 = __builtin_amdgcn_mfma_f32_16x16x32_f16(A[0][1], B1, a0, 0, 0, 0);
        a1 = __builtin_amdgcn_mfma_f32_16x16x32_f16(A[1][1], B1, a1, 0, 0, 0);
        a2 = __builtin_amdgcn_mfma_f32_16x16x32_f16(A[2][1], B1, a2, 0, 0, 0);
        a3 = __builtin_amdgcn_mfma_f32_16x16x32_f16(A[3][1], B1, a3, 0, 0, 0);

        // ---- x value for step t (rotate before read; uniform branch) ----
        if ((t & 3) == 0 && t) {
            xq = xq2;
            int o = t + 4; if (o > TT - 4) o = TT - 4;
            xq2 = *(const float4*)(xrow + o);
        }
        const float xv = ((const float*)&xq)[t & 3];

        // ---- static tile select (8 cndmask) ----
        const f32x4 ga = cp ? a1 : a0;   // pair0: tiles w / w+4
        const f32x4 gb = cp ? a3 : a2;   // pair1: tiles w+8 / w+12

        // ---- pair0 epilogue (gates scaled by MFMA; x/bias exact fp32) ----
        const float zi0 = ga[0] + __builtin_fmaf(swA[0], xv, sbA[0]);
        const float zf0 = ga[1] + __builtin_fmaf(swA[1], xv, sbA[1]);
        const float zg0 = ga[2] + __builtin_fmaf(swA[2], xv, sbA[2]);
        const float zo0 = ga[3] + __builtin_fmaf(swA[3], xv, sbA[3]);
        const float Ei0 = __builtin_amdgcn_exp2f(zi0);
        const float Ef0 = __builtin_amdgcn_exp2f(zf0);
        const float Eg0 = __builtin_amdgcn_exp2f(zg0);
        const float Eo0 = __builtin_amdgcn_exp2f(zo0);
        const float P0  = (1.0f + Ei0) * (1.0f + Eg0);
        const float Q0  = 1.0f + Ef0;
        const float n0  = __builtin_fmaf(c0, P0, (Eg0 - 1.0f) * Q0);
        c0 = n0 * __builtin_amdgcn_rcpf(P0 * Q0);
        const float Ec0 = __builtin_amdgcn_exp2f(fminf(LOG2E2 * c0, 80.0f));
        hA = (Ec0 - 1.0f) * __builtin_amdgcn_rcpf((1.0f + Eo0) * (1.0f + Ec0));

        // ---- pair1 epilogue (independent chain; pad units harmless) ----
        const float zi1 = gb[0] + __builtin_fmaf(swB[0], xv, sbB[0]);
        const float zf1 = gb[1] + __builtin_fmaf(swB[1], xv, sbB[1]);
        const float zg1 = gb[2] + __builtin_fmaf(swB[2], xv, sbB[2]);
        const float zo1 = gb[3] + __builtin_fmaf(swB[3], xv, sbB[3]);
        const float Ei1 = __builtin_amdgcn_exp2f(zi1);
        const float Ef1 = __builtin_amdgcn_exp2f(zf1);
        const float Eg1 = __builtin_amdgcn_exp2f(zg1);
        const float Eo1 = __builtin_amdgcn_exp2f(zo1);
        const float P1  = (1.0f + Ei1) * (1.0f + Eg1);
        const float Q1  = 1.0f + Ef1;
        const float n1  = __builtin_fmaf(c1, P1, (Eg1 - 1.0f) * Q1);
        c1 = n1 * __builtin_amdgcn_rcpf(P1 * Q1);
        const float Ec1 = __builtin_amdgcn_exp2f(fminf(LOG2E2 * c1, 80.0f));
        hBv = (Ec1 - 1.0f) * __builtin_amdgcn_rcpf((1.0f + Eo1) * (1.0f + Ec1));

        // ---- publish h (unguarded: j1 pad -> zero-A slots 50..63 < KP) ----
        const int nb = (t + 1) & 1;
        hb[nb][bl][j0] = (_Float16)hA;
        hb[nb][bl][j1] = (_Float16)hBv;
        __syncthreads();
    }

    // ---- head: out[b] = b_lin + sum_j W_lin[j] * h[j][b] ----
    redH[j0][bl] = wlinA * hA;
    if (jv1) redH[j1][bl] = wlinB * hBv;
    __syncthreads();
    if (tid < BW) {
        float s = b_lin[0];
        #pragma unroll 10
        for (int jj = 0; jj < H; ++jj) s += redH[jj][tid];
        out[b0 + tid] = s;
    }
}

extern "C" void kernel_launch(void* const* d_in, const int* in_sizes, int n_in,
                              void* d_out, int out_size, void* d_ws, size_t ws_size,
                              hipStream_t stream) {
    const float* x     = (const float*)d_in[0];
    const float* W_ih  = (const float*)d_in[1];
    const float* W_hh  = (const float*)d_in[2];
    const float* b_ih  = (const float*)d_in[3];
    const float* b_hh  = (const float*)d_in[4];
    const float* W_lin = (const float*)d_in[5];
    const float* b_lin = (const float*)d_in[6];
    float* out = (float*)d_out;

    dim3 grid(BATCH / BW);    // 256 blocks, 1 per CU
    dim3 block(NTHR);         // 4 identical waves
    lstm_kernel<<<grid, block, 0, stream>>>(x, W_ih, W_hh, b_ih, b_hh,
                                            W_lin, b_lin, out);
}

// Round 13
// 344.877 us; speedup vs baseline: 1.3177x; 1.3177x over previous
//
#include <hip/hip_runtime.h>

// LSTM B=2048, T=1024, H=50. Round 13: R11 + precomputed x-table (no global
// memory ops inside the recurrence loop -> no vmcnt(0) drain at the barrier).
//
// grid=256 (1 block/CU), block=448 = 7 waves (1.75/SIMD), BW=8 batches.
// Wave w owns permuted gate-row tiles 2w, 2w+1 (rows n'=4j+g). Lane (kq,L15):
// pair (unit j = 8w + 4*(L15>>3) + kq, batch bl = L15&7); L15/L15+8 read the
// same hb row (free broadcast). A = scaled W' single f16 in VGPRs
// (i,f,o rows x -log2e; g rows x +2log2e -> exp2-only epilogue).
//   A K-slots: 0-49 W_hh | 50-55 zero (pad-unit h) | 56 wih_hi | 57 wih_hi |
//              58 wih_lo | 59 bias_hi | 60 bias_lo | 61-63 zero.
// B1 slice of kq==3 lanes (k=56..63) = {x_hi, x_lo, x_hi, 1, 1, 0,0,0}: a
// pure function of (bl,t) -> precomputed XT[t][bl]={x_hi,x_lo} (32 KB LDS).
// Per step kq==3 lanes rebuild B1 from XT via cndmask; hb x-writes deleted.
// Epilogue: fused 7-trans (R11). h written unguarded (pad j -> zero-A slots).
// Loop unrolled x2 (static double-buffer addressing). One barrier per step.

#define H     50
#define TT    1024
#define BATCH 2048
#define BW    8
#define NTHR  448     // 7 waves
#define KP    80      // f16 per hb row (40-word stride, measured conflict-free)

typedef float        f32x4 __attribute__((ext_vector_type(4)));
typedef _Float16     f16x8 __attribute__((ext_vector_type(8)));
typedef unsigned int u32x4 __attribute__((ext_vector_type(4)));

__global__ __launch_bounds__(NTHR, 1) void lstm_kernel(
    const float* __restrict__ x,      // [B, T]
    const float* __restrict__ W_ih,   // [200]
    const float* __restrict__ W_hh,   // [200, 50]
    const float* __restrict__ b_ih,   // [200]
    const float* __restrict__ b_hh,   // [200]
    const float* __restrict__ W_lin,  // [50]
    const float* __restrict__ b_lin,  // [1]
    float* __restrict__ out)          // [B]
{
    __shared__ _Float16     hb[2][BW][KP];   // h^T, double-buffered
    __shared__ unsigned int XT[TT][BW];      // packed {x_hi, x_lo} per (t, b)
    __shared__ float        redH[H][BW];     // head reduction

    const int tid  = threadIdx.x;
    const int wave = tid >> 6;
    const int lane = tid & 63;
    const int L15  = lane & 15;
    const int kq   = lane >> 4;
    const int bl   = L15 & 7;
    const int b0   = blockIdx.x * BW;

    const int t0 = 2 * wave;                 // tiles t0, t0+1 (wave 6: 12,13)

    const float LOG2E  = 1.4426950408889634f;
    const float LOG2E2 = 2.8853900817779268f;

    // ---- A fragments: scaled permuted W' rows, single f16, in VGPRs ----
    f16x8 A[2][2];
    #pragma unroll
    for (int tt = 0; tt < 2; ++tt) {
        const int m  = (t0 + tt) * 16 + L15;
        const int jm = m >> 2, gm = m & 3;
        const bool v = (jm < H);
        const float s = (gm == 2) ? LOG2E2 : -LOG2E;
        float swih = 0.f, sbias = 0.f;
        if (v) {
            swih  = s * W_ih[gm * H + jm];
            sbias = s * (b_ih[gm * H + jm] + b_hh[gm * H + jm]);
        }
        const _Float16 whi = (_Float16)swih;
        const _Float16 wlo = (_Float16)(swih - (float)whi);
        const _Float16 bhi = (_Float16)sbias;
        const _Float16 blo = (_Float16)(sbias - (float)bhi);
        #pragma unroll
        for (int kf = 0; kf < 2; ++kf) {
            f16x8 vv;
            #pragma unroll
            for (int e = 0; e < 8; ++e) {
                const int k = kf * 32 + kq * 8 + e;
                _Float16 val = (_Float16)0.f;
                if (v) {
                    if (k < H)        val = (_Float16)(s * W_hh[(gm * H + jm) * H + k]);
                    else if (k == 56) val = whi;
                    else if (k == 57) val = whi;
                    else if (k == 58) val = wlo;
                    else if (k == 59) val = bhi;
                    else if (k == 60) val = blo;
                }
                vv[e] = val;
            }
            A[tt][kf] = vv;
        }
    }

    // ---- this lane's pair ----
    const int  j  = 8 * wave + ((L15 >> 3) << 2) + kq;   // 0..55 (50-55 pad)
    const bool jv = (j < H);
    const float wlin = jv ? W_lin[j] : 0.f;
    const bool k3 = (kq == 3);

    // ---- init: zero hb; fill XT from global x (coalesced in t) ----
    for (int i = tid; i < 2 * BW * KP; i += NTHR)
        ((_Float16*)hb)[i] = (_Float16)0.f;
    for (int i = tid; i < TT * BW; i += NTHR) {
        const int bb = i >> 10, t = i & 1023;
        const float xv = x[(size_t)(b0 + bb) * TT + t];
        const _Float16 xh = (_Float16)xv;
        const _Float16 xl = (_Float16)(xv - (float)xh);
        XT[t][bb] = (unsigned int)*(const unsigned short*)&xh |
                    ((unsigned int)*(const unsigned short*)&xl << 16);
    }

    float c = 0.f, hlast = 0.f;
    __syncthreads();

    #pragma unroll 1
    for (int tbase = 0; tbase < TT; tbase += 2) {
        #pragma unroll
        for (int half = 0; half < 2; ++half) {
            const int t = tbase + half;
            const _Float16* hp = &hb[half][bl][0];        // cur buffer
            _Float16*       np = &hb[half ^ 1][bl][0];    // next buffer

            // ---- B fragments ----
            f16x8 B0 = *(const f16x8*)(hp + kq * 8);      // k 0..31
            u32x4 Bh = *(const u32x4*)(hp + 32 + kq * 8); // k 32..63 (as u32)
            const unsigned int xt = XT[t][bl];            // {x_hi, x_lo}
            // kq==3 lanes: slice = {xh, xl, xh, 1, 1, 0, 0, 0}
            u32x4 Bm;
            Bm[0] = k3 ? xt : Bh[0];
            Bm[1] = k3 ? ((xt & 0xFFFFu) | 0x3C000000u) : Bh[1];
            Bm[2] = k3 ? 0x00003C00u : Bh[2];
            Bm[3] = k3 ? 0u : Bh[3];
            const f16x8 B1 = __builtin_bit_cast(f16x8, Bm);

            // ---- 4 MFMAs: two independent 2-deep chains ----
            const f32x4 z = {0.f, 0.f, 0.f, 0.f};
            f32x4 a0 = __builtin_amdgcn_mfma_f32_16x16x32_f16(A[0][0], B0, z, 0, 0, 0);
            f32x4 a1 = __builtin_amdgcn_mfma_f32_16x16x32_f16(A[1][0], B0, z, 0, 0, 0);
            a0 = __builtin_amdgcn_mfma_f32_16x16x32_f16(A[0][1], B1, a0, 0, 0, 0);
            a1 = __builtin_amdgcn_mfma_f32_16x16x32_f16(A[1][1], B1, a1, 0, 0, 0);

            // ---- select this lane's accumulator (tile t0 vs t0+1) ----
            const bool lo = (L15 < 8);
            const float gi = lo ? a0[0] : a1[0];
            const float gf = lo ? a0[1] : a1[1];
            const float gg = lo ? a0[2] : a1[2];
            const float go = lo ? a0[3] : a1[3];

            // ---- fused epilogue: 7 trans ----
            const float Ei = __builtin_amdgcn_exp2f(gi);
            const float Ef = __builtin_amdgcn_exp2f(gf);
            const float Eg = __builtin_amdgcn_exp2f(gg);
            const float Eo = __builtin_amdgcn_exp2f(go);
            const float P  = (1.0f + Ei) * (1.0f + Eg);
            const float Q  = 1.0f + Ef;
            const float num = __builtin_fmaf(c, P, (Eg - 1.0f) * Q);
            c = num * __builtin_amdgcn_rcpf(P * Q);
            const float ca = fminf(LOG2E2 * c, 80.0f);
            const float Ec = __builtin_amdgcn_exp2f(ca);
            const float h  = (Ec - 1.0f) *
                __builtin_amdgcn_rcpf((1.0f + Eo) * (1.0f + Ec));
            hlast = h;

            np[j] = (_Float16)h;   // unguarded: pad j -> zero-A slots 50-55
            __syncthreads();
        }
    }

    // ---- head: out[b] = b_lin + sum_j W_lin[j] * h[j][b] ----
    if (jv) redH[j][bl] = wlin * hlast;
    __syncthreads();
    if (tid < BW) {
        float s = b_lin[0];
        #pragma unroll 10
        for (int jj = 0; jj < H; ++jj) s += redH[jj][tid];
        out[b0 + tid] = s;
    }
}

extern "C" void kernel_launch(void* const* d_in, const int* in_sizes, int n_in,
                              void* d_out, int out_size, void* d_ws, size_t ws_size,
                              hipStream_t stream) {
    const float* x     = (const float*)d_in[0];
    const float* W_ih  = (const float*)d_in[1];
    const float* W_hh  = (const float*)d_in[2];
    const float* b_ih  = (const float*)d_in[3];
    const float* b_hh  = (const float*)d_in[4];
    const float* W_lin = (const float*)d_in[5];
    const float* b_lin = (const float*)d_in[6];
    float* out = (float*)d_out;

    dim3 grid(BATCH / BW);    // 256 blocks, 1 per CU
    dim3 block(NTHR);         // 7 waves
    lstm_kernel<<<grid, block, 0, stream>>>(x, W_ih, W_hh, b_ih, b_hh,
                                            W_lin, b_lin, out);
}